// Round 1
// 158.584 us; speedup vs baseline: 1.0383x; 1.0383x over previous
//
#include <hip/hip_runtime.h>
#include <hip/hip_bf16.h>
#include <math.h>

#define NB 4
#define CC 128
#define HH 64
#define WW 64
#define HEADS 4
#define KS 7
#define DD 32
#define HW 4096
#define MTOT 16384   // NB*HW

typedef unsigned short BF;
typedef short short8 __attribute__((ext_vector_type(8)));
typedef float floatx4 __attribute__((ext_vector_type(4)));

__device__ __forceinline__ float gelu_f(float x) {
    return 0.5f * x * (1.0f + erff(x * 0.70710678118654752440f));
}

__device__ __forceinline__ BF f2bf(float f) {
    union { float f; unsigned u; } a; a.f = f;
    unsigned u = a.u;
    unsigned r = u + 0x7FFFu + ((u >> 16) & 1u);   // RNE
    return (BF)(r >> 16);
}

__device__ __forceinline__ float bf2f(BF v) {
    return __uint_as_float(((unsigned)v) << 16);
}

#define LDK 40      // padded LDS row, K=32 tiles (bf16)
#define LDK128 136  // padded LDS row, K=128 tiles (bf16)

// ---------------- LN1 transpose-tile + one-time weight prep -----------
__global__ __launch_bounds__(256) void ln1t_kernel(
    const float* __restrict__ x, const float* __restrict__ w,
    const float* __restrict__ b, BF* __restrict__ out,
    float* __restrict__ part,
    const float* __restrict__ qkv_w, const float* __restrict__ conv1_w,
    const float* __restrict__ conv2_w, const float* __restrict__ proj_w,
    const float* __restrict__ fc1_w, const float* __restrict__ fc2_w,
    BF* __restrict__ qkvT, BF* __restrict__ c1T, BF* __restrict__ c2T,
    BF* __restrict__ projT2, BF* __restrict__ fc1T2, BF* __restrict__ fc2T2)
{
    const int blk = blockIdx.x;
    const int t  = threadIdx.x;

    if (blk >= 512) {   // ---- weight prep (one-time, 204800 elems) ----
        for (int idx = (blk - 512) * 256 + t; idx < 204800; idx += 32768) {
            if (idx < 49152) {                    // qkvT [384][128]
                int l = idx, n = l >> 7, k = l & 127;
                qkvT[l] = f2bf(qkv_w[k * 384 + n]);
            } else if (idx < 53248) {             // c1T [32][128]
                int l = idx - 49152, n = l >> 7, k = l & 127;
                c1T[l] = f2bf(conv1_w[k * 32 + n]);
            } else if (idx < 57344) {             // c2T [128][32]
                int l = idx - 53248, n = l >> 5, k = l & 31;
                c2T[l] = f2bf(conv2_w[k * 128 + n]);
            } else if (idx < 73728) {             // projT2 [4][128][32]
                int l = idx - 57344, kk = l & 31, n = (l >> 5) & 127, ks = l >> 12;
                projT2[l] = f2bf(proj_w[(ks * 32 + kk) * 128 + n]);
            } else if (idx < 139264) {            // fc1T2 [4][512][32]
                int l = idx - 73728, kk = l & 31, n = (l >> 5) & 511, ks = l >> 14;
                fc1T2[l] = f2bf(fc1_w[(ks * 32 + kk) * 512 + n]);
            } else {                              // fc2T2 [16][128][32]
                int l = idx - 139264, kk = l & 31, n = (l >> 5) & 127, ks = l >> 12;
                fc2T2[l] = f2bf(fc2_w[(ks * 32 + kk) * 128 + n]);
            }
        }
        return;
    }

    __shared__ float xt[128][33];
    __shared__ float mus[32], rss[32];
    const int n  = blk >> 7;
    const int p0 = (blk & 127) * 32;
    if (blk < 4 && t < 128) part[blk * CC + t] = 0.f;   // zero CA partials

    {
        int pp = t & 31, c8 = t >> 5;
        #pragma unroll 4
        for (int it = 0; it < 16; it++) {
            int c = it * 8 + c8;
            xt[c][pp] = x[(size_t)(n * CC + c) * HW + p0 + pp];
        }
    }
    __syncthreads();
    {
        int pp2 = t >> 3, cb = t & 7;
        float s = 0.f;
        #pragma unroll
        for (int u = 0; u < 16; u++) s += xt[cb + u * 8][pp2];
        s += __shfl_xor(s, 1); s += __shfl_xor(s, 2); s += __shfl_xor(s, 4);
        float mu = s * (1.0f / CC);
        float v = 0.f;
        #pragma unroll
        for (int u = 0; u < 16; u++) { float d = xt[cb + u * 8][pp2] - mu; v += d * d; }
        v += __shfl_xor(v, 1); v += __shfl_xor(v, 2); v += __shfl_xor(v, 4);
        if (cb == 0) { mus[pp2] = mu; rss[pp2] = rsqrtf(v * (1.0f / CC) + 1e-5f); }
    }
    __syncthreads();
    {
        #pragma unroll
        for (int it = 0; it < 2; it++) {
            int pp2 = (t >> 4) + it * 16;
            int c0  = (t & 15) * 8;
            float mu = mus[pp2], rs = rss[pp2];
            int m = n * HW + p0 + pp2;
            short8 o;
            #pragma unroll
            for (int u = 0; u < 8; u++)
                o[u] = (short)f2bf((xt[c0 + u][pp2] - mu) * rs * w[c0 + u] + b[c0 + u]);
            *(short8*)(out + (size_t)m * CC + c0) = o;
        }
    }
}

// ---------------- phase2: qkv GEMM (2 row-tiles/block) + conv-MLP -----
__global__ __launch_bounds__(256) void phase2(
    const BF* __restrict__ xn, const BF* __restrict__ qkvT,
    const float* __restrict__ qkv_b, BF* __restrict__ qkv_out,
    const BF* __restrict__ c1T, const float* __restrict__ b1,
    const BF* __restrict__ c2T, const float* __restrict__ b2,
    BF* __restrict__ tout, float* __restrict__ part)
{
    __shared__ __align__(16) char smem[26624];
    const int bid = blockIdx.x;
    const int t = threadIdx.x;
    const int w = t >> 6, lane = t & 63, q = lane >> 4, r16 = lane & 15;

    if (bid < 768) {
        BF* Bl = (BF*)smem;   // [64][LDK128]
        const int col0 = (bid % 6) * 64;
        const int row0 = (bid / 6) * 128;
        {
            int nn = t >> 2;
            int kk = (t & 3) * 32;
            const BF* src = qkvT + (size_t)(col0 + nn) * 128 + kk;
            #pragma unroll
            for (int u = 0; u < 4; u++)
                *(uint4*)(Bl + nn * LDK128 + kk + u * 8) = *(const uint4*)(src + u * 8);
        }
        __syncthreads();
        #pragma unroll
        for (int half = 0; half < 2; half++) {
            floatx4 acc[4] = {};
            const BF* arow = xn + (size_t)(row0 + half * 64 + w * 16 + r16) * CC;
            #pragma unroll
            for (int ks = 0; ks < 4; ks++) {
                short8 af = *(const short8*)(arow + ks * 32 + q * 8);
                #pragma unroll
                for (int nt = 0; nt < 4; nt++) {
                    short8 bf = *(const short8*)(Bl + (nt * 16 + r16) * LDK128 + ks * 32 + q * 8);
                    acc[nt] = __builtin_amdgcn_mfma_f32_16x16x32_bf16(af, bf, acc[nt], 0, 0, 0);
                }
            }
            #pragma unroll
            for (int nt = 0; nt < 4; nt++) {
                int col = col0 + nt * 16 + r16;
                float bv = qkv_b[col];
                #pragma unroll
                for (int reg = 0; reg < 4; reg++) {
                    int row = row0 + half * 64 + w * 16 + q * 4 + reg;
                    qkv_out[(size_t)row * 384 + col] = f2bf(acc[nt][reg] + bv);
                }
            }
        }
        return;
    }
    // ---- conv branch ----
    BF*    W1l = (BF*)smem;                  // [32][LDK128]  8704 B
    BF*    W2l = (BF*)(smem + 8704);         // [128][LDK]   10240 B
    BF*    Hl  = (BF*)(smem + 18944);        // [64][LDK]     5120 B
    float* red = (float*)(smem + 24064);     // [4][128]      2048 B
    const int row0 = (bid - 768) * 64;
    {
        #pragma unroll
        for (int it = 0; it < 2; it++) {
            int idx = it * 256 + t;
            int nn = idx >> 4, u = idx & 15;
            *(uint4*)(W1l + nn * LDK128 + u * 8) = *(const uint4*)(c1T + nn * 128 + u * 8);
        }
    }
    {
        #pragma unroll
        for (int it = 0; it < 2; it++) {
            int idx = it * 256 + t;
            int nn = idx >> 2, u = idx & 3;
            *(uint4*)(W2l + nn * LDK + u * 8) = *(const uint4*)(c2T + nn * 32 + u * 8);
        }
    }
    __syncthreads();
    floatx4 a1[2] = {};
    const BF* arow = xn + (size_t)(row0 + w * 16 + r16) * CC;
    #pragma unroll
    for (int ks = 0; ks < 4; ks++) {
        short8 af = *(const short8*)(arow + ks * 32 + q * 8);
        #pragma unroll
        for (int nt = 0; nt < 2; nt++) {
            short8 bf = *(const short8*)(W1l + (nt * 16 + r16) * LDK128 + ks * 32 + q * 8);
            a1[nt] = __builtin_amdgcn_mfma_f32_16x16x32_bf16(af, bf, a1[nt], 0, 0, 0);
        }
    }
    #pragma unroll
    for (int nt = 0; nt < 2; nt++) {
        int col = nt * 16 + r16;
        float bv = b1[col];
        #pragma unroll
        for (int reg = 0; reg < 4; reg++)
            Hl[(w * 16 + q * 4 + reg) * LDK + col] = f2bf(gelu_f(a1[nt][reg] + bv));
    }
    __syncthreads();
    floatx4 a2[8] = {};
    short8 af2 = *(const short8*)(Hl + (w * 16 + r16) * LDK + q * 8);
    #pragma unroll
    for (int nt = 0; nt < 8; nt++) {
        short8 bf = *(const short8*)(W2l + (nt * 16 + r16) * LDK + q * 8);
        a2[nt] = __builtin_amdgcn_mfma_f32_16x16x32_bf16(af2, bf, a2[nt], 0, 0, 0);
    }
    #pragma unroll
    for (int nt = 0; nt < 8; nt++) {
        int col = nt * 16 + r16;
        float bv = b2[col];
        float s = 0.f;
        #pragma unroll
        for (int reg = 0; reg < 4; reg++) {
            int row = row0 + w * 16 + q * 4 + reg;
            float v = a2[nt][reg] + bv;
            tout[(size_t)row * CC + col] = f2bf(v);
            s += v;
        }
        s += __shfl_xor(s, 16);
        s += __shfl_xor(s, 32);
        if (lane < 16) red[w * 128 + col] = s;
    }
    __syncthreads();
    if (t < 128) {
        float cs = red[t] + red[128 + t] + red[256 + t] + red[384 + t];
        atomicAdd(&part[(row0 >> 12) * CC + t], cs);
    }
}

// ---------------- MFMA neighborhood attention (tile-pruned) -----------
// Block 1024 (extra): computes the per-image CA micro-MLP once (gl[4][128])
// so tail blocks no longer replicate its serial 128-dot on their critical
// path. Runs concurrently with the attention blocks.
__global__ __launch_bounds__(256) void na_mfma_kernel(
    const BF* __restrict__ qkv, const float* __restrict__ rpb,
    BF* __restrict__ outp,
    const float* __restrict__ part,
    const float* __restrict__ ca1_w, const float* __restrict__ ca1_b,
    const float* __restrict__ ca2_w, const float* __restrict__ ca2_b,
    float* __restrict__ glw)
{
    __shared__ __align__(16) BF Kt[224][40];
    __shared__ __align__(16) BF Vt[32][232];
    __shared__ __align__(16) BF Qb[64][40];
    __shared__ __align__(16) BF Pl[4][16][232];
    __shared__ float rb[169];

    const int b = blockIdx.x;
    const int t = threadIdx.x;

    if (b == 1024) {   // ---- CA micro-MLP, once per launch ----
        float* gsm = (float*)Kt;    // [4][128] f32, aliases Kt
        float* h1s = (float*)Qb;    // [28] f32, aliases Qb
        if (t < 128) {
            #pragma unroll
            for (int nn = 0; nn < 4; nn++)
                gsm[nn * 128 + t] = part[nn * CC + t] * (1.0f / HW);
        }
        __syncthreads();
        if (t < 224) {              // 28 (n,r) pairs x 8 lanes each
            int pair = t >> 3, s = t & 7;
            int nn = pair / 7, r = pair % 7;
            float a = 0.f;
            #pragma unroll
            for (int k = 0; k < 16; k++)
                a += gsm[nn * 128 + s + k * 8] * ca1_w[(s + k * 8) * 7 + r];
            a += __shfl_xor(a, 1); a += __shfl_xor(a, 2); a += __shfl_xor(a, 4);
            if (s == 0) h1s[pair] = fmaxf(a + ca1_b[r], 0.f);
        }
        __syncthreads();
        if (t < 128) {
            #pragma unroll
            for (int nn = 0; nn < 4; nn++) {
                float o = ca2_b[t];
                #pragma unroll
                for (int r = 0; r < 7; r++) o += h1s[nn * 7 + r] * ca2_w[r * 128 + t];
                glw[nn * CC + t] = 1.0f / (1.0f + expf(-o));
            }
        }
        return;
    }

    const int h = b & 3;
    const int tile = b >> 2;
    const int n = tile >> 6;
    const int ti = (tile >> 3) & 7, tj = tile & 7;
    const int w = t >> 6, lane = t & 63, quad = lane >> 4, r16 = lane & 15;
    const int i0 = ti * 8, j0 = tj * 8;
    const int wi0 = max(i0 - 3, 0), wj0 = max(j0 - 3, 0);
    const int R  = min(wi0 + 13, 63) - wi0 + 1;
    const int Rj = min(wj0 + 13, 63) - wj0 + 1;

    for (int idx = t; idx < 896; idx += 256) {
        int key = idx >> 2, ch = idx & 3;
        int kr = key >> 4, kc = key & 15;
        uint4 v = {0u, 0u, 0u, 0u};
        if (kr < R && kc < Rj) {
            size_t pix = (size_t)((n * HH + wi0 + kr) * WW + wj0 + kc);
            v = *(const uint4*)(qkv + pix * 384 + 128 + h * DD + ch * 8);
        }
        *(uint4*)&Kt[key][ch * 8] = v;
    }
    for (int idx = t; idx < 896; idx += 256) {
        int key = idx >> 2, ch = idx & 3;
        int kr = key >> 4, kc = key & 15;
        if (kr < R && kc < Rj) {
            size_t pix = (size_t)((n * HH + wi0 + kr) * WW + wj0 + kc);
            uint4 v = *(const uint4*)(qkv + pix * 384 + 256 + h * DD + ch * 8);
            const BF* pv = (const BF*)&v;
            #pragma unroll
            for (int u = 0; u < 8; u++) Vt[ch * 8 + u][key] = pv[u];
        } else {
            #pragma unroll
            for (int u = 0; u < 8; u++) Vt[ch * 8 + u][key] = 0;
        }
    }
    {
        int q = t >> 2, ch = t & 3;
        size_t mq = (size_t)((n * HH + i0 + (q >> 3)) * WW + j0 + (q & 7));
        *(uint4*)&Qb[q][ch * 8] = *(const uint4*)(qkv + mq * 384 + h * DD + ch * 8);
    }
    if (t < 169) rb[t] = rpb[h * 169 + t];
    __syncthreads();

    // wave's first pixel row -> pruned k-tile base
    const int kt0 = min(max(i0 + 2 * w - 3, 0), HH - KS) - wi0;

    int oi[4], cok[4], bj0[4], ai_[4];
    #pragma unroll
    for (int reg = 0; reg < 4; reg++) {
        int q = w * 16 + quad * 4 + reg;
        int i = i0 + (q >> 3), j = j0 + (q & 7);
        int ni = min(max(i - 3, 0), HH - KS), nj = min(max(j - 3, 0), WW - KS);
        oi[reg]  = ni - wi0;
        ai_[reg] = ni - i + 6;
        int dc = r16 - (nj - wj0);
        cok[reg] = ((unsigned)dc < 7u) ? 1 : 0;
        bj0[reg] = min(max(dc + (nj - j + 6), 0), 12);
    }

    short8 aq = *(const short8*)&Qb[w * 16 + r16][quad * 8];
    floatx4 S[8];
    #pragma unroll
    for (int jt = 0; jt < 8; jt++) {
        floatx4 z = {0.f, 0.f, 0.f, 0.f};
        short8 bk = *(const short8*)&Kt[(kt0 + jt) * 16 + r16][quad * 8];
        S[jt] = __builtin_amdgcn_mfma_f32_16x16x32_bf16(aq, bk, z, 0, 0, 0);
    }
    const float scale = 0.17677669529663688110f;
    #pragma unroll
    for (int jt = 0; jt < 8; jt++) {
        #pragma unroll
        for (int reg = 0; reg < 4; reg++) {
            int dr = kt0 + jt - oi[reg];
            bool ok = ((unsigned)dr < 7u) && cok[reg];
            int bi = min(max(dr + ai_[reg], 0), 12);
            float bias = rb[bi * 13 + bj0[reg]];
            S[jt][reg] = ok ? fmaf(S[jt][reg], scale, bias) : -1e30f;
        }
    }
    float rinv[4];
    #pragma unroll
    for (int reg = 0; reg < 4; reg++) {
        float m = S[0][reg];
        #pragma unroll
        for (int jt = 1; jt < 8; jt++) m = fmaxf(m, S[jt][reg]);
        m = fmaxf(m, __shfl_xor(m, 1));
        m = fmaxf(m, __shfl_xor(m, 2));
        m = fmaxf(m, __shfl_xor(m, 4));
        m = fmaxf(m, __shfl_xor(m, 8));
        float s = 0.f;
        #pragma unroll
        for (int jt = 0; jt < 8; jt++) {
            float e = __expf(S[jt][reg] - m);
            S[jt][reg] = e;
            s += e;
        }
        s += __shfl_xor(s, 1);
        s += __shfl_xor(s, 2);
        s += __shfl_xor(s, 4);
        s += __shfl_xor(s, 8);
        rinv[reg] = 1.0f / s;
    }
    #pragma unroll
    for (int jt = 0; jt < 8; jt++)
        #pragma unroll
        for (int reg = 0; reg < 4; reg++)
            Pl[w][quad * 4 + reg][(kt0 + jt) * 16 + r16] = f2bf(S[jt][reg] * rinv[reg]);
    if (kt0 & 1) {   // zero boundary tiles read by the extra PV chunk
        #pragma unroll
        for (int reg = 0; reg < 4; reg++) {
            Pl[w][quad * 4 + reg][(kt0 - 1) * 16 + r16] = 0;
            Pl[w][quad * 4 + reg][(kt0 + 8) * 16 + r16] = 0;
        }
    }

    const int ks0 = kt0 >> 1;
    const int nch = 4 + (kt0 & 1);
    floatx4 O0 = {0.f, 0.f, 0.f, 0.f}, O1 = {0.f, 0.f, 0.f, 0.f};
    #pragma unroll
    for (int c2 = 0; c2 < 5; c2++) {
        if (c2 < nch) {
            int ks = ks0 + c2;
            short8 ap = *(const short8*)&Pl[w][r16][ks * 32 + quad * 8];
            short8 b0 = *(const short8*)&Vt[r16][ks * 32 + quad * 8];
            short8 b1 = *(const short8*)&Vt[16 + r16][ks * 32 + quad * 8];
            O0 = __builtin_amdgcn_mfma_f32_16x16x32_bf16(ap, b0, O0, 0, 0, 0);
            O1 = __builtin_amdgcn_mfma_f32_16x16x32_bf16(ap, b1, O1, 0, 0, 0);
        }
    }
    #pragma unroll
    for (int reg = 0; reg < 4; reg++) {
        int q = w * 16 + quad * 4 + reg;
        size_t m = (size_t)((n * HH + i0 + (q >> 3)) * WW + j0 + (q & 7));
        outp[m * CC + h * DD + r16]      = f2bf(O0[reg]);
        outp[m * CC + h * DD + 16 + r16] = f2bf(O1[reg]);
    }
}

// ---------------- fused tail: 32 rows/block, wave = column split ------
// grid 512, ~61 KB LDS -> 2 blocks/CU (all resident). Wave w: proj/fc2
// cols [w*32,w*32+32), fc1 cols [w*128,w*128+128); 2 row-tiles per wave
// reuse every B fragment (halves L2 weight traffic vs 16-row blocks).
// CA gate gl is precomputed (na launch) — just a 128-float load here.
// x2 in registers; st overlays xs (xs dead before fc2 epilogue).
__global__ __launch_bounds__(256, 2) void tail_kernel(
    const BF* __restrict__ A, const BF* __restrict__ projT2,
    const float* __restrict__ proj_b, const float* __restrict__ x,
    const BF* __restrict__ tbuf, const float* __restrict__ glw,
    const float* __restrict__ w2, const float* __restrict__ b2,
    const BF* __restrict__ fc1T2, const float* __restrict__ fc1_b,
    const BF* __restrict__ fc2T2, const float* __restrict__ fc2_b,
    float* __restrict__ out)
{
    __shared__ __align__(16) char sarena[17408];    // xs [32][132] f32 / st [128][34] f32
    __shared__ __align__(16) BF ln2l[32][136];      // 8704 B
    __shared__ __align__(16) BF hl[32][520];        // 33280 B
    __shared__ float gl[128];
    __shared__ float S1[2][4][16], S2[2][4][16];

    float* xs = (float*)sarena;    // [p][c] stride 132
    float* st = (float*)sarena;    // [c][p] stride 34

    const int t = threadIdx.x;
    const int w = t >> 6, lane = t & 63, quad = lane >> 4, r16 = lane & 15;
    const int row0 = blockIdx.x * 32;
    const int n = row0 >> 12, p0 = row0 & 4095;

    // ---- stage x tile: 128 c x 32 p, coalesced float4 along p ----
    #pragma unroll
    for (int it = 0; it < 4; it++) {
        int idx4 = it * 256 + t;
        int p4 = idx4 & 7, c = idx4 >> 3;
        float4 v = *(const float4*)(x + (size_t)(n * CC + c) * HW + p0 + p4 * 4);
        xs[(p4 * 4 + 0) * 132 + c] = v.x; xs[(p4 * 4 + 1) * 132 + c] = v.y;
        xs[(p4 * 4 + 2) * 132 + c] = v.z; xs[(p4 * 4 + 3) * 132 + c] = v.w;
    }
    if (t < 128) gl[t] = glw[n * CC + t];

    // ---- proj: wave = 32 rows x 32 cols, B frags reused across tiles ----
    // (no LDS dependence: overlaps with the x staging above)
    floatx4 acc[2][2] = {};
    const BF* ar0 = A + (size_t)(row0 + r16) * CC;
    const BF* ar1 = A + (size_t)(row0 + 16 + r16) * CC;
    #pragma unroll
    for (int ks = 0; ks < 4; ks++) {
        short8 a0 = *(const short8*)(ar0 + ks * 32 + quad * 8);
        short8 a1 = *(const short8*)(ar1 + ks * 32 + quad * 8);
        #pragma unroll
        for (int nt = 0; nt < 2; nt++) {
            int col = w * 32 + nt * 16 + r16;
            short8 bf = *(const short8*)(projT2 + ((size_t)(ks * 128 + col)) * 32 + quad * 8);
            acc[0][nt] = __builtin_amdgcn_mfma_f32_16x16x32_bf16(a0, bf, acc[0][nt], 0, 0, 0);
            acc[1][nt] = __builtin_amdgcn_mfma_f32_16x16x32_bf16(a1, bf, acc[1][nt], 0, 0, 0);
        }
    }
    __syncthreads();   // xs + gl ready

    // ---- x2 (registers) + LN2 stats ----
    float x2r[2][2][4];
    float s1[2][4] = {}, s2[2][4] = {};
    #pragma unroll
    for (int tile = 0; tile < 2; tile++) {
        #pragma unroll
        for (int nt = 0; nt < 2; nt++) {
            int col = w * 32 + nt * 16 + r16;
            float bv = proj_b[col], gv = gl[col];
            #pragma unroll
            for (int reg = 0; reg < 4; reg++) {
                int lr = tile * 16 + quad * 4 + reg;
                float tv = bf2f(tbuf[(size_t)(row0 + lr) * CC + col]);
                float v = acc[tile][nt][reg] + bv + xs[lr * 132 + col] + 0.02f * tv * gv;
                x2r[tile][nt][reg] = v;
                s1[tile][reg] += v; s2[tile][reg] += v * v;
            }
        }
    }
    #pragma unroll
    for (int tile = 0; tile < 2; tile++) {
        #pragma unroll
        for (int reg = 0; reg < 4; reg++) {
            #pragma unroll
            for (int off = 1; off < 16; off <<= 1) {
                s1[tile][reg] += __shfl_xor(s1[tile][reg], off);
                s2[tile][reg] += __shfl_xor(s2[tile][reg], off);
            }
        }
    }
    if (r16 == 0) {
        #pragma unroll
        for (int tile = 0; tile < 2; tile++)
            #pragma unroll
            for (int reg = 0; reg < 4; reg++) {
                S1[tile][w][quad * 4 + reg] = s1[tile][reg];
                S2[tile][w][quad * 4 + reg] = s2[tile][reg];
            }
    }
    __syncthreads();
    float mu[2][4], rr[2][4];
    #pragma unroll
    for (int tile = 0; tile < 2; tile++) {
        #pragma unroll
        for (int reg = 0; reg < 4; reg++) {
            int r = quad * 4 + reg;
            float t1 = S1[tile][0][r] + S1[tile][1][r] + S1[tile][2][r] + S1[tile][3][r];
            float t2 = S2[tile][0][r] + S2[tile][1][r] + S2[tile][2][r] + S2[tile][3][r];
            mu[tile][reg] = t1 * (1.0f / CC);
            float var = t2 * (1.0f / CC) - mu[tile][reg] * mu[tile][reg];
            rr[tile][reg] = rsqrtf(var + 1e-5f);
        }
    }
    #pragma unroll
    for (int tile = 0; tile < 2; tile++) {
        #pragma unroll
        for (int nt = 0; nt < 2; nt++) {
            int col = w * 32 + nt * 16 + r16;
            float wv = w2[col], bv2 = b2[col];
            #pragma unroll
            for (int reg = 0; reg < 4; reg++) {
                int lr = tile * 16 + quad * 4 + reg;
                ln2l[lr][col] = f2bf((x2r[tile][nt][reg] - mu[tile][reg]) * rr[tile][reg] * wv + bv2);
            }
        }
    }
    __syncthreads();   // ln2l ready

    // ---- fc1: wave = 32 rows x 128 cols, B frags reused across tiles ----
    short8 af1[2][4];
    #pragma unroll
    for (int tile = 0; tile < 2; tile++)
        #pragma unroll
        for (int ks = 0; ks < 4; ks++)
            af1[tile][ks] = *(const short8*)&ln2l[tile * 16 + r16][ks * 32 + quad * 8];
    floatx4 c1[2][8] = {};
    #pragma unroll
    for (int ks = 0; ks < 4; ks++) {
        #pragma unroll
        for (int nt = 0; nt < 8; nt++) {
            int col = w * 128 + nt * 16 + r16;
            short8 bf = *(const short8*)(fc1T2 + ((size_t)(ks * 512 + col)) * 32 + quad * 8);
            c1[0][nt] = __builtin_amdgcn_mfma_f32_16x16x32_bf16(af1[0][ks], bf, c1[0][nt], 0, 0, 0);
            c1[1][nt] = __builtin_amdgcn_mfma_f32_16x16x32_bf16(af1[1][ks], bf, c1[1][nt], 0, 0, 0);
        }
    }
    #pragma unroll
    for (int tile = 0; tile < 2; tile++) {
        #pragma unroll
        for (int nt = 0; nt < 8; nt++) {
            int col = w * 128 + nt * 16 + r16;
            float bv = fc1_b[col];
            #pragma unroll
            for (int reg = 0; reg < 4; reg++) {
                int lr = tile * 16 + quad * 4 + reg;
                hl[lr][col] = f2bf(gelu_f(c1[tile][nt][reg] + bv));
            }
        }
    }
    __syncthreads();   // hl ready

    // ---- fc2: wave = 32 rows x 32 cols, K=512, B frags reused ----
    floatx4 c2[2][2] = {};
    #pragma unroll
    for (int ks = 0; ks < 16; ks++) {
        short8 h0 = *(const short8*)&hl[r16][ks * 32 + quad * 8];
        short8 h1 = *(const short8*)&hl[16 + r16][ks * 32 + quad * 8];
        #pragma unroll
        for (int nt = 0; nt < 2; nt++) {
            int col = w * 32 + nt * 16 + r16;
            short8 bf = *(const short8*)(fc2T2 + ((size_t)(ks * 128 + col)) * 32 + quad * 8);
            c2[0][nt] = __builtin_amdgcn_mfma_f32_16x16x32_bf16(h0, bf, c2[0][nt], 0, 0, 0);
            c2[1][nt] = __builtin_amdgcn_mfma_f32_16x16x32_bf16(h1, bf, c2[1][nt], 0, 0, 0);
        }
    }
    // xs dead since the ln2l barrier; st overlay safe without extra barrier
    #pragma unroll
    for (int tile = 0; tile < 2; tile++) {
        #pragma unroll
        for (int nt = 0; nt < 2; nt++) {
            int col = w * 32 + nt * 16 + r16;
            float bv = fc2_b[col];
            #pragma unroll
            for (int reg = 0; reg < 4; reg++) {
                int lr = tile * 16 + quad * 4 + reg;
                st[col * 34 + lr] = c2[tile][nt][reg] + bv + x2r[tile][nt][reg];
            }
        }
    }
    __syncthreads();
    {   // coalesced NCHW store: 128 cols x 32 p
        int col = t >> 1, half = t & 1;
        float* dst = out + (size_t)(n * CC + col) * HW + p0 + half * 16;
        #pragma unroll
        for (int u = 0; u < 4; u++) {
            float4 v;
            v.x = st[col * 34 + half * 16 + u * 4 + 0];
            v.y = st[col * 34 + half * 16 + u * 4 + 1];
            v.z = st[col * 34 + half * 16 + u * 4 + 2];
            v.w = st[col * 34 + half * 16 + u * 4 + 3];
            *(float4*)(dst + u * 4) = v;
        }
    }
}

extern "C" void kernel_launch(void* const* d_in, const int* in_sizes, int n_in,
                              void* d_out, int out_size, void* d_ws, size_t ws_size,
                              hipStream_t stream)
{
    const float* x       = (const float*)d_in[0];
    const float* ln1_w   = (const float*)d_in[1];
    const float* ln1_b   = (const float*)d_in[2];
    const float* ln2_w   = (const float*)d_in[3];
    const float* ln2_b   = (const float*)d_in[4];
    const float* qkv_w   = (const float*)d_in[5];
    const float* qkv_b   = (const float*)d_in[6];
    const float* proj_w  = (const float*)d_in[7];
    const float* proj_b  = (const float*)d_in[8];
    const float* rpb     = (const float*)d_in[9];
    const float* conv1_w = (const float*)d_in[10];
    const float* conv1_b = (const float*)d_in[11];
    const float* conv2_w = (const float*)d_in[12];
    const float* conv2_b = (const float*)d_in[13];
    const float* ca1_w   = (const float*)d_in[14];
    const float* ca1_b   = (const float*)d_in[15];
    const float* ca2_w   = (const float*)d_in[16];
    const float* ca2_b   = (const float*)d_in[17];
    const float* fc1_w   = (const float*)d_in[18];
    const float* fc1_b   = (const float*)d_in[19];
    const float* fc2_w   = (const float*)d_in[20];
    const float* fc2_b   = (const float*)d_in[21];
    float* out = (float*)d_out;

    char* ws = (char*)d_ws;
    BF*    xn_bf   = (BF*)(ws);                  // M*128*2 = 4 MB
    BF*    qkv_bf  = (BF*)(ws + 4194304);        // M*384*2 = 12 MB
    BF*    t_bf    = (BF*)(ws + 16777216);       // M*128*2 = 4 MB
    BF*    na_bf   = (BF*)(ws + 20971520);       // M*128*2 = 4 MB
    float* part    = (float*)(ws + 25165824);    // 2 KB
    BF*    qkvT    = (BF*)(ws + 25167872);       // 98304 B
    BF*    c1T     = (BF*)(ws + 25266176);       // 8192 B
    BF*    c2T     = (BF*)(ws + 25274368);       // 8192 B
    BF*    projT2  = (BF*)(ws + 25282560);       // 32768 B
    BF*    fc1T2   = (BF*)(ws + 25315328);       // 131072 B
    BF*    fc2T2   = (BF*)(ws + 25446400);       // 131072 B
    float* glw     = (float*)(ws + 25577472);    // 2 KB   CA gate [4][128]

    // 1. LN1 transpose-tile + one-time weight prep (blocks 512..639)
    ln1t_kernel<<<640, 256, 0, stream>>>(x, ln1_w, ln1_b, xn_bf, part,
        qkv_w, conv1_w, conv2_w, proj_w, fc1_w, fc2_w,
        qkvT, c1T, c2T, projT2, fc1T2, fc2T2);
    // 2. qkv GEMM (2 row-tiles/block) + conv-MLP, one launch
    phase2<<<1024, 256, 0, stream>>>(xn_bf, qkvT, qkv_b, qkv_bf,
                                     c1T, conv1_b, c2T, conv2_b, t_bf, part);
    // 3. MFMA neighborhood attention (tile-pruned) + CA MLP (block 1024)
    na_mfma_kernel<<<1025, 256, 0, stream>>>(qkv_bf, rpb, na_bf,
                                             part, ca1_w, ca1_b, ca2_w, ca2_b, glw);
    // 4. fused tail: 32 rows/block, grid 512, B-traffic halved
    tail_kernel<<<512, 256, 0, stream>>>(na_bf, projT2, proj_b, x, t_bf, glw,
                                         ln2_w, ln2_b, fc1T2, fc1_b,
                                         fc2T2, fc2_b, out);
}